// Round 7
// baseline (47.855 us; speedup 1.0000x reference)
//
#include <hip/hip_runtime.h>

#define NPIX    76800      // 240*320
#define WIDTH   320
#define NS      9
#define NTOT    (NPIX*NS)  // 691200
#define VDIM    320

// launch: identity mapping (tid = g), 256 threads/block, 2700 blocks
#define BLOCK   256
#define NBLK    (NTOT / BLOCK)          // 2700
#define NXCD    8
#define SWZ_Q   (NBLK / NXCD)           // 337
#define SWZ_R   (NBLK % NXCD)           // 4

// output offsets (all float32 elements, concatenated in return order)
#define OFF_FV  0
#define OFF_FW  691200
#define OFF_RP  1382400
#define OFF_D   3456000
#define OFF_I   3532800
#define OFF_W8  20121600
#define OFF_C   25651200

typedef float f32x4 __attribute__((ext_vector_type(4)));

__global__ __launch_bounds__(BLOCK, 8) void extractor_kernel(
    const float* __restrict__ depth,
    const float* __restrict__ extr,      // 4x4 row-major
    const float* __restrict__ intr,      // 3x3 row-major
    const float* __restrict__ vol,       // 320^3
    const float* __restrict__ wvol,      // 320^3
    const float* __restrict__ origin,    // 3
    const float* __restrict__ resolution,// 1
    float* __restrict__ out)
{
    __shared__ f32x4 lds4[128 * 6];      // 12 KiB: half-block inds staging, reused for w8

    // ---- bijective chunked XCD swizzle (2700 = 8*337 + 4) ----
    const int bid  = blockIdx.x;
    const int xcd  = bid & (NXCD - 1);
    const int base = bid >> 3;
    const int swz  = (xcd < SWZ_R ? xcd * (SWZ_Q + 1)
                                  : SWZ_R * (SWZ_Q + 1) + (xcd - SWZ_R) * SWZ_Q) + base;

    const int t   = threadIdx.x;
    const int gB  = swz * BLOCK;         // block's base output index
    const int tid = gB + t;              // identity: output index == work index
    const int p   = tid / 9;             // pixel (row-major)
    const int s   = tid - p * 9;         // sample 0..8

    const int row = p / WIDTH;           // v
    const int col = p - row * WIDTH;     // u

    const float z = depth[p];

    // --- 3x3 inverse of intrinsics (adjugate; uniform values) ---
    const float a00=intr[0], a01=intr[1], a02=intr[2];
    const float a10=intr[3], a11=intr[4], a12=intr[5];
    const float a20=intr[6], a21=intr[7], a22=intr[8];
    const float det = a00*(a11*a22 - a12*a21)
                    - a01*(a10*a22 - a12*a20)
                    + a02*(a10*a21 - a11*a20);
    const float id = 1.0f / det;
    const float i00 = (a11*a22 - a12*a21)*id;
    const float i01 = (a02*a21 - a01*a22)*id;
    const float i02 = (a01*a12 - a02*a11)*id;
    const float i10 = (a12*a20 - a10*a22)*id;
    const float i11 = (a00*a22 - a02*a20)*id;
    const float i12 = (a02*a10 - a00*a12)*id;
    const float i20 = (a10*a21 - a11*a20)*id;
    const float i21 = (a01*a20 - a00*a21)*id;
    const float i22 = (a00*a11 - a01*a10)*id;

    // pts_p = (u*z, v*z, z)
    const float up = (float)col * z;
    const float vp = (float)row * z;
    const float pcx = i00*up + i01*vp + i02*z;
    const float pcy = i10*up + i11*vp + i12*z;
    const float pcz = i20*up + i21*vp + i22*z;

    // world coords = (E @ [pc,1])[:3]
    const float cwx = extr[0]*pcx + extr[1]*pcy + extr[2]*pcz  + extr[3];
    const float cwy = extr[4]*pcx + extr[5]*pcy + extr[6]*pcz  + extr[7];
    const float cwz = extr[8]*pcx + extr[9]*pcy + extr[10]*pcz + extr[11];

    const float ox = origin[0], oy = origin[1], oz = origin[2];
    const float res = resolution[0];

    // voxel coords
    const float cvx = (cwx - ox) / res;
    const float cvy = (cwy - oy) / res;
    const float cvz = (cwz - oz) / res;
    const float evx = (extr[3]  - ox) / res;
    const float evy = (extr[7]  - oy) / res;
    const float evz = (extr[11] - oz) / res;

    float dx = cvx - evx, dy = cvy - evy, dz = cvz - evz;
    const float nrm = sqrtf(dx*dx + dy*dy + dz*dz);
    const float dn  = fmaxf(nrm, 1e-12f);
    dx /= dn; dy /= dn; dz /= dn;

    const float offs = (float)(s - 4);   // offs in [-4,4]
    const float pt[3] = { cvx + offs*dx, cvy + offs*dy, cvz + offs*dz };

    // --- trilinear setup ---
    float alpha[3], nb[3], fidx[3];
    #pragma unroll
    for (int k = 0; k < 3; ++k) {
        const float f  = floorf(pt[k]);
        const float c  = f + 0.5f;
        const float df = c - pt[k];
        nb[k]    = (df > 0.0f) ? 1.0f : ((df < 0.0f) ? -1.0f : 0.0f);
        alpha[k] = fabsf(pt[k] - c);
        fidx[k]  = f;
    }

    // phase 1: all addresses + weights + validity (no loads yet)
    int   lin[8];
    float wgt8[8];
    bool  valid8[8];
    float indsbuf[24];
    #pragma unroll
    for (int c = 0; c < 8; ++c) {
        float wgt = 1.0f;
        bool valid = true;
        int ii[3];
        #pragma unroll
        for (int k = 0; k < 3; ++k) {
            const float bit = ((c >> (2 - k)) & 1) ? 1.0f : 0.0f;
            wgt *= (bit > 0.0f) ? alpha[k] : (1.0f - alpha[k]);
            const float fi = fidx[k] + bit * nb[k];
            valid = valid && (fi >= 0.0f) && (fi < (float)VDIM);
            const float fc = fminf(fmaxf(fi, 0.0f), (float)(VDIM - 1));
            ii[k] = (int)fc;
            indsbuf[c*3 + k] = (float)ii[k];
        }
        lin[c]    = (ii[0]*VDIM + ii[1])*VDIM + ii[2];
        wgt8[c]   = wgt;
        valid8[c] = valid;
    }

    // phase 2: issue all 16 gathers back-to-back (max memory-level parallelism)
    float v8[8], wv8[8];
    #pragma unroll
    for (int c = 0; c < 8; ++c) v8[c]  = vol[lin[c]];
    #pragma unroll
    for (int c = 0; c < 8; ++c) wv8[c] = wvol[lin[c]];

    // phase 3: gather-independent direct stores (coalesced under identity map)
    out[OFF_RP + tid*3 + 0] = pt[0];
    out[OFF_RP + tid*3 + 1] = pt[1];
    out[OFF_RP + tid*3 + 2] = pt[2];
    if (s == 0) {
        out[OFF_D + p] = z;
        out[OFF_C + p*3 + 0] = cwx;
        out[OFF_C + p*3 + 1] = cwy;
        out[OFF_C + p*3 + 2] = cwz;
    }

    // phase 4: inds via LDS transpose, two half-block passes (12 KiB LDS)
    f32x4* outI = reinterpret_cast<f32x4*>(out + OFF_I) + gB*6;
    if (t < 128) {
        #pragma unroll
        for (int c = 0; c < 6; ++c) {
            f32x4 v4 = { indsbuf[c*4+0], indsbuf[c*4+1], indsbuf[c*4+2], indsbuf[c*4+3] };
            lds4[t*6 + c] = v4;
        }
    }
    __syncthreads();
    #pragma unroll
    for (int it = 0; it < 3; ++it)
        outI[it*BLOCK + t] = lds4[it*BLOCK + t];
    __syncthreads();
    if (t >= 128) {
        #pragma unroll
        for (int c = 0; c < 6; ++c) {
            f32x4 v4 = { indsbuf[c*4+0], indsbuf[c*4+1], indsbuf[c*4+2], indsbuf[c*4+3] };
            lds4[(t-128)*6 + c] = v4;
        }
    }
    __syncthreads();
    #pragma unroll
    for (int it = 0; it < 3; ++it)
        outI[768 + it*BLOCK + t] = lds4[it*BLOCK + t];
    __syncthreads();

    // phase 5: w8 via LDS (reuse buffer, 8 KiB) -> coalesced contiguous write
    f32x4 w0 = { wgt8[0], wgt8[1], wgt8[2], wgt8[3] };
    f32x4 w1 = { wgt8[4], wgt8[5], wgt8[6], wgt8[7] };
    lds4[t*2 + 0] = w0;
    lds4[t*2 + 1] = w1;
    __syncthreads();
    f32x4* outW = reinterpret_cast<f32x4*>(out + OFF_W8) + gB*2;
    outW[t]         = lds4[t];
    outW[BLOCK + t] = lds4[BLOCK + t];

    // phase 6: consume gathers (latest possible wait on the scattered loads)
    float fv = 0.0f, fw = 0.0f;
    #pragma unroll
    for (int c = 0; c < 8; ++c) {
        if (valid8[c]) { fv += v8[c] * wgt8[c]; fw += wv8[c] * wgt8[c]; }
    }
    out[OFF_FV + tid] = fv;
    out[OFF_FW + tid] = fw;
}

extern "C" void kernel_launch(void* const* d_in, const int* in_sizes, int n_in,
                              void* d_out, int out_size, void* d_ws, size_t ws_size,
                              hipStream_t stream) {
    const float* depth      = (const float*)d_in[0];
    const float* extr       = (const float*)d_in[1];
    const float* intr       = (const float*)d_in[2];
    const float* vol        = (const float*)d_in[3];
    const float* wvol       = (const float*)d_in[4];
    const float* origin     = (const float*)d_in[5];
    const float* resolution = (const float*)d_in[6];
    float* out = (float*)d_out;

    extractor_kernel<<<NBLK, BLOCK, 0, stream>>>(
        depth, extr, intr, vol, wvol, origin, resolution, out);
}

// Round 8
// 46.850 us; speedup vs baseline: 1.0215x; 1.0215x over previous
//
#include <hip/hip_runtime.h>

#define NPIX    76800      // 240*320
#define WIDTH   320
#define NS      9
#define NTOT    (NPIX*NS)  // 691200
#define VDIM    320
#define NVOX    (VDIM*VDIM*VDIM)

// launch: identity mapping (tid = g), 256 threads/block, 2700 blocks
#define BLOCK   256
#define NBLK    (NTOT / BLOCK)          // 2700
#define NXCD    8
#define SWZ_Q   (NBLK / NXCD)           // 337
#define SWZ_R   (NBLK % NXCD)           // 4

// output offsets (all float32 elements, concatenated in return order)
#define OFF_FV  0
#define OFF_FW  691200
#define OFF_RP  1382400
#define OFF_D   3456000
#define OFF_I   3532800
#define OFF_W8  20121600
#define OFF_C   25651200

typedef float f32x4 __attribute__((ext_vector_type(4)));
typedef float f32x2 __attribute__((ext_vector_type(2)));

__global__ __launch_bounds__(BLOCK, 6) void extractor_kernel(
    const float* __restrict__ depth,
    const float* __restrict__ extr,      // 4x4 row-major
    const float* __restrict__ intr,      // 3x3 row-major
    const float* __restrict__ vol,       // 320^3
    const float* __restrict__ wvol,      // 320^3
    const float* __restrict__ origin,    // 3
    const float* __restrict__ resolution,// 1
    float* __restrict__ out)
{
    __shared__ f32x4 lds4[BLOCK * 6];    // 24 KiB: staging for inds, reused for w8

    // ---- bijective chunked XCD swizzle (2700 = 8*337 + 4) ----
    const int bid  = blockIdx.x;
    const int xcd  = bid & (NXCD - 1);
    const int base = bid >> 3;
    const int swz  = (xcd < SWZ_R ? xcd * (SWZ_Q + 1)
                                  : SWZ_R * (SWZ_Q + 1) + (xcd - SWZ_R) * SWZ_Q) + base;

    const int t   = threadIdx.x;
    const int gB  = swz * BLOCK;         // block's base output index
    const int tid = gB + t;              // identity: output index == work index
    const int p   = tid / 9;             // pixel (row-major)
    const int s   = tid - p * 9;         // sample 0..8

    const int row = p / WIDTH;           // v
    const int col = p - row * WIDTH;     // u

    const float z = depth[p];

    // --- 3x3 inverse of intrinsics (adjugate; uniform values) ---
    const float a00=intr[0], a01=intr[1], a02=intr[2];
    const float a10=intr[3], a11=intr[4], a12=intr[5];
    const float a20=intr[6], a21=intr[7], a22=intr[8];
    const float det = a00*(a11*a22 - a12*a21)
                    - a01*(a10*a22 - a12*a20)
                    + a02*(a10*a21 - a11*a20);
    const float id = 1.0f / det;
    const float i00 = (a11*a22 - a12*a21)*id;
    const float i01 = (a02*a21 - a01*a22)*id;
    const float i02 = (a01*a12 - a02*a11)*id;
    const float i10 = (a12*a20 - a10*a22)*id;
    const float i11 = (a00*a22 - a02*a20)*id;
    const float i12 = (a02*a10 - a00*a12)*id;
    const float i20 = (a10*a21 - a11*a20)*id;
    const float i21 = (a01*a20 - a00*a21)*id;
    const float i22 = (a00*a11 - a01*a10)*id;

    // pts_p = (u*z, v*z, z)
    const float up = (float)col * z;
    const float vp = (float)row * z;
    const float pcx = i00*up + i01*vp + i02*z;
    const float pcy = i10*up + i11*vp + i12*z;
    const float pcz = i20*up + i21*vp + i22*z;

    // world coords = (E @ [pc,1])[:3]
    const float cwx = extr[0]*pcx + extr[1]*pcy + extr[2]*pcz  + extr[3];
    const float cwy = extr[4]*pcx + extr[5]*pcy + extr[6]*pcz  + extr[7];
    const float cwz = extr[8]*pcx + extr[9]*pcy + extr[10]*pcz + extr[11];

    const float ox = origin[0], oy = origin[1], oz = origin[2];
    const float res = resolution[0];

    // voxel coords
    const float cvx = (cwx - ox) / res;
    const float cvy = (cwy - oy) / res;
    const float cvz = (cwz - oz) / res;
    const float evx = (extr[3]  - ox) / res;
    const float evy = (extr[7]  - oy) / res;
    const float evz = (extr[11] - oz) / res;

    float dx = cvx - evx, dy = cvy - evy, dz = cvz - evz;
    const float nrm = sqrtf(dx*dx + dy*dy + dz*dz);
    const float dn  = fmaxf(nrm, 1e-12f);
    dx /= dn; dy /= dn; dz /= dn;

    const float offs = (float)(s - 4);   // offs in [-4,4]
    const float pt[3] = { cvx + offs*dx, cvy + offs*dy, cvz + offs*dz };

    // --- trilinear setup ---
    float alpha[3], nb[3], fidx[3];
    #pragma unroll
    for (int k = 0; k < 3; ++k) {
        const float f  = floorf(pt[k]);
        const float c  = f + 0.5f;
        const float df = c - pt[k];
        nb[k]    = (df > 0.0f) ? 1.0f : ((df < 0.0f) ? -1.0f : 0.0f);
        alpha[k] = fabsf(pt[k] - c);
        fidx[k]  = f;
    }

    // z corner indexes are shared by all 4 (x,y) pairs
    const float fz0 = fidx[2];
    const float fz1 = fidx[2] + nb[2];
    const bool  vz0 = (fz0 >= 0.0f) && (fz0 < (float)VDIM);
    const bool  vz1 = (fz1 >= 0.0f) && (fz1 < (float)VDIM);
    const int   iz0 = (int)fminf(fmaxf(fz0, 0.0f), (float)(VDIM - 1));
    const int   iz1 = (int)fminf(fmaxf(fz1, 0.0f), (float)(VDIM - 1));
    const int   lo  = min(iz0, iz1);
    const int   sel0 = iz0 - lo;         // 0 or 1
    const int   sel1 = iz1 - lo;
    const float az   = alpha[2];
    const float wz0  = 1.0f - az, wz1 = az;

    // phase 1: 4 pair-addresses + weights + validity
    int   pbase[4];
    int   poff[4];                       // unaligned-guard shift (0 or 1)
    float wxy[4];
    bool  vxy[4];
    float indsbuf[24];
    #pragma unroll
    for (int q4 = 0; q4 < 4; ++q4) {
        const float bx = (q4 >> 1) ? 1.0f : 0.0f;
        const float by = (q4 & 1)  ? 1.0f : 0.0f;
        const float fx = fidx[0] + bx * nb[0];
        const float fy = fidx[1] + by * nb[1];
        const bool  vx = (fx >= 0.0f) && (fx < (float)VDIM);
        const bool  vy = (fy >= 0.0f) && (fy < (float)VDIM);
        const int   ix = (int)fminf(fmaxf(fx, 0.0f), (float)(VDIM - 1));
        const int   iy = (int)fminf(fmaxf(fy, 0.0f), (float)(VDIM - 1));
        const float wx = (bx > 0.0f) ? alpha[0] : (1.0f - alpha[0]);
        const float wy = (by > 0.0f) ? alpha[1] : (1.0f - alpha[1]);
        const int   b  = (ix * VDIM + iy) * VDIM;
        pbase[q4] = b;
        poff[q4]  = (b + lo == NVOX - 1) ? 1 : 0;   // only possible when sel0==sel1==0
        wxy[q4]   = wx * wy;
        vxy[q4]   = vx && vy;
        // inds: corners 2*q4 (z-bit 0) and 2*q4+1 (z-bit 1)
        indsbuf[(2*q4)*3 + 0]   = (float)ix;
        indsbuf[(2*q4)*3 + 1]   = (float)iy;
        indsbuf[(2*q4)*3 + 2]   = (float)iz0;
        indsbuf[(2*q4+1)*3 + 0] = (float)ix;
        indsbuf[(2*q4+1)*3 + 1] = (float)iy;
        indsbuf[(2*q4+1)*3 + 2] = (float)iz1;
    }

    // phase 2: 8 paired gathers (dwordx2), all issued back-to-back
    f32x2 v2[4], wv2[4];
    #pragma unroll
    for (int q4 = 0; q4 < 4; ++q4)
        v2[q4]  = *reinterpret_cast<const f32x2*>(vol  + pbase[q4] + lo - poff[q4]);
    #pragma unroll
    for (int q4 = 0; q4 < 4; ++q4)
        wv2[q4] = *reinterpret_cast<const f32x2*>(wvol + pbase[q4] + lo - poff[q4]);

    // phase 3: gather-independent direct stores (coalesced under identity map)
    out[OFF_RP + tid*3 + 0] = pt[0];
    out[OFF_RP + tid*3 + 1] = pt[1];
    out[OFF_RP + tid*3 + 2] = pt[2];
    if (s == 0) {
        out[OFF_D + p] = z;
        out[OFF_C + p*3 + 0] = cwx;
        out[OFF_C + p*3 + 1] = cwy;
        out[OFF_C + p*3 + 2] = cwz;
    }

    // phase 4: inds via LDS transpose -> fully coalesced 24 KB contiguous write
    #pragma unroll
    for (int c = 0; c < 6; ++c) {
        f32x4 v4 = { indsbuf[c*4+0], indsbuf[c*4+1], indsbuf[c*4+2], indsbuf[c*4+3] };
        lds4[t*6 + c] = v4;
    }
    __syncthreads();
    f32x4* outI = reinterpret_cast<f32x4*>(out + OFF_I) + gB*6;
    #pragma unroll
    for (int it = 0; it < 6; ++it)
        outI[it*BLOCK + t] = lds4[it*BLOCK + t];
    __syncthreads();

    // phase 5: w8 via LDS (reuse buffer) -> coalesced contiguous write
    {
        const float w00 = wxy[0]*wz0, w01 = wxy[0]*wz1;
        const float w10 = wxy[1]*wz0, w11 = wxy[1]*wz1;
        const float w20 = wxy[2]*wz0, w21 = wxy[2]*wz1;
        const float w30 = wxy[3]*wz0, w31 = wxy[3]*wz1;
        f32x4 w0 = { w00, w01, w10, w11 };
        f32x4 w1 = { w20, w21, w30, w31 };
        lds4[t*2 + 0] = w0;
        lds4[t*2 + 1] = w1;
    }
    __syncthreads();
    f32x4* outW = reinterpret_cast<f32x4*>(out + OFF_W8) + gB*2;
    outW[t]         = lds4[t];
    outW[BLOCK + t] = lds4[BLOCK + t];

    // phase 6: consume gathers
    float fv = 0.0f, fw = 0.0f;
    #pragma unroll
    for (int q4 = 0; q4 < 4; ++q4) {
        const float wz0e = (vxy[q4] && vz0) ? wxy[q4] * wz0 : 0.0f;
        const float wz1e = (vxy[q4] && vz1) ? wxy[q4] * wz1 : 0.0f;
        const int   e0 = sel0 + poff[q4];
        const int   e1 = sel1 + poff[q4];
        fv += v2[q4][e0]  * wz0e + v2[q4][e1]  * wz1e;
        fw += wv2[q4][e0] * wz0e + wv2[q4][e1] * wz1e;
    }
    out[OFF_FV + tid] = fv;
    out[OFF_FW + tid] = fw;
}

extern "C" void kernel_launch(void* const* d_in, const int* in_sizes, int n_in,
                              void* d_out, int out_size, void* d_ws, size_t ws_size,
                              hipStream_t stream) {
    const float* depth      = (const float*)d_in[0];
    const float* extr       = (const float*)d_in[1];
    const float* intr       = (const float*)d_in[2];
    const float* vol        = (const float*)d_in[3];
    const float* wvol       = (const float*)d_in[4];
    const float* origin     = (const float*)d_in[5];
    const float* resolution = (const float*)d_in[6];
    float* out = (float*)d_out;

    extractor_kernel<<<NBLK, BLOCK, 0, stream>>>(
        depth, extr, intr, vol, wvol, origin, resolution, out);
}

// Round 9
// 42.778 us; speedup vs baseline: 1.1187x; 1.0952x over previous
//
#include <hip/hip_runtime.h>

#define NPIX    76800      // 240*320
#define WIDTH   320
#define NS      9
#define NTOT    (NPIX*NS)  // 691200
#define VDIM    320
#define NVOX    (VDIM*VDIM*VDIM)

// launch: identity mapping (tid = g), 256 threads/block, 2700 blocks
#define BLOCK   256
#define NBLK    (NTOT / BLOCK)          // 2700
#define NXCD    8
#define SWZ_Q   (NBLK / NXCD)           // 337
#define SWZ_R   (NBLK % NXCD)           // 4

// output offsets (all float32 elements, concatenated in return order)
#define OFF_FV  0
#define OFF_FW  691200
#define OFF_RP  1382400
#define OFF_D   3456000
#define OFF_I   3532800
#define OFF_W8  20121600
#define OFF_C   25651200

typedef float f32x4 __attribute__((ext_vector_type(4)));
typedef float f32x2 __attribute__((ext_vector_type(2)));

__global__ __launch_bounds__(BLOCK, 6) void extractor_kernel(
    const float* __restrict__ depth,
    const float* __restrict__ extr,      // 4x4 row-major
    const float* __restrict__ intr,      // 3x3 row-major
    const float* __restrict__ vol,       // 320^3
    const float* __restrict__ wvol,      // 320^3
    const float* __restrict__ origin,    // 3
    const float* __restrict__ resolution,// 1
    float* __restrict__ out)
{
    __shared__ f32x4 lds4[BLOCK * 6];    // 24 KiB: staging for inds, reused for w8

    // ---- bijective chunked XCD swizzle (2700 = 8*337 + 4) ----
    const int bid  = blockIdx.x;
    const int xcd  = bid & (NXCD - 1);
    const int base = bid >> 3;
    const int swz  = (xcd < SWZ_R ? xcd * (SWZ_Q + 1)
                                  : SWZ_R * (SWZ_Q + 1) + (xcd - SWZ_R) * SWZ_Q) + base;

    const int t   = threadIdx.x;
    const int gB  = swz * BLOCK;         // block's base output index
    const int tid = gB + t;              // identity: output index == work index
    const int p   = tid / 9;             // pixel (row-major)
    const int s   = tid - p * 9;         // sample 0..8

    const int row = p / WIDTH;           // v
    const int col = p - row * WIDTH;     // u

    const float z = depth[p];

    // --- 3x3 inverse of intrinsics (adjugate; uniform values) ---
    const float a00=intr[0], a01=intr[1], a02=intr[2];
    const float a10=intr[3], a11=intr[4], a12=intr[5];
    const float a20=intr[6], a21=intr[7], a22=intr[8];
    const float det = a00*(a11*a22 - a12*a21)
                    - a01*(a10*a22 - a12*a20)
                    + a02*(a10*a21 - a11*a20);
    const float id = 1.0f / det;
    const float i00 = (a11*a22 - a12*a21)*id;
    const float i01 = (a02*a21 - a01*a22)*id;
    const float i02 = (a01*a12 - a02*a11)*id;
    const float i10 = (a12*a20 - a10*a22)*id;
    const float i11 = (a00*a22 - a02*a20)*id;
    const float i12 = (a02*a10 - a00*a12)*id;
    const float i20 = (a10*a21 - a11*a20)*id;
    const float i21 = (a01*a20 - a00*a21)*id;
    const float i22 = (a00*a11 - a01*a10)*id;

    // pts_p = (u*z, v*z, z)
    const float up = (float)col * z;
    const float vp = (float)row * z;
    const float pcx = i00*up + i01*vp + i02*z;
    const float pcy = i10*up + i11*vp + i12*z;
    const float pcz = i20*up + i21*vp + i22*z;

    // world coords = (E @ [pc,1])[:3]
    const float cwx = extr[0]*pcx + extr[1]*pcy + extr[2]*pcz  + extr[3];
    const float cwy = extr[4]*pcx + extr[5]*pcy + extr[6]*pcz  + extr[7];
    const float cwz = extr[8]*pcx + extr[9]*pcy + extr[10]*pcz + extr[11];

    const float ox = origin[0], oy = origin[1], oz = origin[2];
    const float res = resolution[0];

    // voxel coords
    const float cvx = (cwx - ox) / res;
    const float cvy = (cwy - oy) / res;
    const float cvz = (cwz - oz) / res;
    const float evx = (extr[3]  - ox) / res;
    const float evy = (extr[7]  - oy) / res;
    const float evz = (extr[11] - oz) / res;

    float dx = cvx - evx, dy = cvy - evy, dz = cvz - evz;
    const float nrm = sqrtf(dx*dx + dy*dy + dz*dz);
    const float dn  = fmaxf(nrm, 1e-12f);
    dx /= dn; dy /= dn; dz /= dn;

    const float offs = (float)(s - 4);   // offs in [-4,4]
    const float pt[3] = { cvx + offs*dx, cvy + offs*dy, cvz + offs*dz };

    // --- trilinear setup ---
    float alpha[3], nb[3], fidx[3];
    #pragma unroll
    for (int k = 0; k < 3; ++k) {
        const float f  = floorf(pt[k]);
        const float c  = f + 0.5f;
        const float df = c - pt[k];
        nb[k]    = (df > 0.0f) ? 1.0f : ((df < 0.0f) ? -1.0f : 0.0f);
        alpha[k] = fabsf(pt[k] - c);
        fidx[k]  = f;
    }

    // z corner indexes are shared by all 4 (x,y) pairs
    const float fz0 = fidx[2];
    const float fz1 = fidx[2] + nb[2];
    const bool  vz0 = (fz0 >= 0.0f) && (fz0 < (float)VDIM);
    const bool  vz1 = (fz1 >= 0.0f) && (fz1 < (float)VDIM);
    const int   iz0 = (int)fminf(fmaxf(fz0, 0.0f), (float)(VDIM - 1));
    const int   iz1 = (int)fminf(fmaxf(fz1, 0.0f), (float)(VDIM - 1));
    const int   lo  = min(iz0, iz1);
    const int   sel0 = iz0 - lo;         // 0 or 1
    const int   sel1 = iz1 - lo;
    const float az   = alpha[2];
    const float wz0  = 1.0f - az, wz1 = az;

    // phase 1: 4 pair-addresses + weights + validity
    int   pbase[4];
    int   poff[4];                       // unaligned-guard shift (0 or 1)
    float wxy[4];
    bool  vxy[4];
    float indsbuf[24];
    #pragma unroll
    for (int q4 = 0; q4 < 4; ++q4) {
        const float bx = (q4 >> 1) ? 1.0f : 0.0f;
        const float by = (q4 & 1)  ? 1.0f : 0.0f;
        const float fx = fidx[0] + bx * nb[0];
        const float fy = fidx[1] + by * nb[1];
        const bool  vx = (fx >= 0.0f) && (fx < (float)VDIM);
        const bool  vy = (fy >= 0.0f) && (fy < (float)VDIM);
        const int   ix = (int)fminf(fmaxf(fx, 0.0f), (float)(VDIM - 1));
        const int   iy = (int)fminf(fmaxf(fy, 0.0f), (float)(VDIM - 1));
        const float wx = (bx > 0.0f) ? alpha[0] : (1.0f - alpha[0]);
        const float wy = (by > 0.0f) ? alpha[1] : (1.0f - alpha[1]);
        const int   b  = (ix * VDIM + iy) * VDIM;
        pbase[q4] = b;
        poff[q4]  = (b + lo == NVOX - 1) ? 1 : 0;   // only possible when sel0==sel1==0
        wxy[q4]   = wx * wy;
        vxy[q4]   = vx && vy;
        // inds: corners 2*q4 (z-bit 0) and 2*q4+1 (z-bit 1)
        indsbuf[(2*q4)*3 + 0]   = (float)ix;
        indsbuf[(2*q4)*3 + 1]   = (float)iy;
        indsbuf[(2*q4)*3 + 2]   = (float)iz0;
        indsbuf[(2*q4+1)*3 + 0] = (float)ix;
        indsbuf[(2*q4+1)*3 + 1] = (float)iy;
        indsbuf[(2*q4+1)*3 + 2] = (float)iz1;
    }

    // phase 2: 8 paired gathers (dwordx2), all issued back-to-back
    f32x2 v2[4], wv2[4];
    #pragma unroll
    for (int q4 = 0; q4 < 4; ++q4)
        v2[q4]  = *reinterpret_cast<const f32x2*>(vol  + pbase[q4] + lo - poff[q4]);
    #pragma unroll
    for (int q4 = 0; q4 < 4; ++q4)
        wv2[q4] = *reinterpret_cast<const f32x2*>(wvol + pbase[q4] + lo - poff[q4]);

    // phase 3: gather-independent direct stores (small, partial-line -> keep cached)
    out[OFF_RP + tid*3 + 0] = pt[0];
    out[OFF_RP + tid*3 + 1] = pt[1];
    out[OFF_RP + tid*3 + 2] = pt[2];
    if (s == 0) {
        out[OFF_D + p] = z;
        out[OFF_C + p*3 + 0] = cwx;
        out[OFF_C + p*3 + 1] = cwy;
        out[OFF_C + p*3 + 2] = cwz;
    }

    // phase 4: inds via LDS transpose -> coalesced full-line NT stream (66 MB)
    #pragma unroll
    for (int c = 0; c < 6; ++c) {
        f32x4 v4 = { indsbuf[c*4+0], indsbuf[c*4+1], indsbuf[c*4+2], indsbuf[c*4+3] };
        lds4[t*6 + c] = v4;
    }
    __syncthreads();
    f32x4* outI = reinterpret_cast<f32x4*>(out + OFF_I) + gB*6;
    #pragma unroll
    for (int it = 0; it < 6; ++it)
        __builtin_nontemporal_store(lds4[it*BLOCK + t], outI + it*BLOCK + t);
    __syncthreads();

    // phase 5: w8 via LDS (reuse buffer) -> coalesced full-line NT stream (22 MB)
    {
        const float w00 = wxy[0]*wz0, w01 = wxy[0]*wz1;
        const float w10 = wxy[1]*wz0, w11 = wxy[1]*wz1;
        const float w20 = wxy[2]*wz0, w21 = wxy[2]*wz1;
        const float w30 = wxy[3]*wz0, w31 = wxy[3]*wz1;
        f32x4 w0 = { w00, w01, w10, w11 };
        f32x4 w1 = { w20, w21, w30, w31 };
        lds4[t*2 + 0] = w0;
        lds4[t*2 + 1] = w1;
    }
    __syncthreads();
    f32x4* outW = reinterpret_cast<f32x4*>(out + OFF_W8) + gB*2;
    __builtin_nontemporal_store(lds4[t],         outW + t);
    __builtin_nontemporal_store(lds4[BLOCK + t], outW + BLOCK + t);

    // phase 6: consume gathers; fv/fw are lane-consecutive dwords (full lines) -> NT
    float fv = 0.0f, fw = 0.0f;
    #pragma unroll
    for (int q4 = 0; q4 < 4; ++q4) {
        const float wz0e = (vxy[q4] && vz0) ? wxy[q4] * wz0 : 0.0f;
        const float wz1e = (vxy[q4] && vz1) ? wxy[q4] * wz1 : 0.0f;
        const int   e0 = sel0 + poff[q4];
        const int   e1 = sel1 + poff[q4];
        fv += v2[q4][e0]  * wz0e + v2[q4][e1]  * wz1e;
        fw += wv2[q4][e0] * wz0e + wv2[q4][e1] * wz1e;
    }
    __builtin_nontemporal_store(fv, out + OFF_FV + tid);
    __builtin_nontemporal_store(fw, out + OFF_FW + tid);
}

extern "C" void kernel_launch(void* const* d_in, const int* in_sizes, int n_in,
                              void* d_out, int out_size, void* d_ws, size_t ws_size,
                              hipStream_t stream) {
    const float* depth      = (const float*)d_in[0];
    const float* extr       = (const float*)d_in[1];
    const float* intr       = (const float*)d_in[2];
    const float* vol        = (const float*)d_in[3];
    const float* wvol       = (const float*)d_in[4];
    const float* origin     = (const float*)d_in[5];
    const float* resolution = (const float*)d_in[6];
    float* out = (float*)d_out;

    extractor_kernel<<<NBLK, BLOCK, 0, stream>>>(
        depth, extr, intr, vol, wvol, origin, resolution, out);
}

// Round 10
// 42.021 us; speedup vs baseline: 1.1388x; 1.0180x over previous
//
#include <hip/hip_runtime.h>

#define NPIX    76800      // 240*320
#define WIDTH   320
#define NS      9
#define NTOT    (NPIX*NS)  // 691200
#define VDIM    320
#define NVOX    (VDIM*VDIM*VDIM)

// launch: identity mapping (tid = g), 256 threads/block, 2700 blocks
#define BLOCK   256
#define NBLK    (NTOT / BLOCK)          // 2700
#define NXCD    8
#define SWZ_Q   (NBLK / NXCD)           // 337
#define SWZ_R   (NBLK % NXCD)           // 4

// output offsets (all float32 elements, concatenated in return order)
#define OFF_FV  0
#define OFF_FW  691200
#define OFF_RP  1382400
#define OFF_D   3456000
#define OFF_I   3532800
#define OFF_W8  20121600
#define OFF_C   25651200

typedef float f32x4 __attribute__((ext_vector_type(4)));
typedef float f32x2 __attribute__((ext_vector_type(2)));

__global__ __launch_bounds__(BLOCK, 6) void extractor_kernel(
    const float* __restrict__ depth,
    const float* __restrict__ extr,      // 4x4 row-major
    const float* __restrict__ intr,      // 3x3 row-major
    const float* __restrict__ vol,       // 320^3
    const float* __restrict__ wvol,      // 320^3
    const float* __restrict__ origin,    // 3
    const float* __restrict__ resolution,// 1
    float* __restrict__ out)
{
    __shared__ f32x4 lds4[BLOCK * 6];    // 24 KiB; each wave owns a 384-float4 slice

    // ---- bijective chunked XCD swizzle (2700 = 8*337 + 4) ----
    const int bid  = blockIdx.x;
    const int xcd  = bid & (NXCD - 1);
    const int base = bid >> 3;
    const int swz  = (xcd < SWZ_R ? xcd * (SWZ_Q + 1)
                                  : SWZ_R * (SWZ_Q + 1) + (xcd - SWZ_R) * SWZ_Q) + base;

    const int t   = threadIdx.x;
    const int gB  = swz * BLOCK;         // block's base output index
    const int tid = gB + t;              // identity: output index == work index
    const int p   = tid / 9;             // pixel (row-major)
    const int s   = tid - p * 9;         // sample 0..8

    const int row = p / WIDTH;           // v
    const int col = p - row * WIDTH;     // u

    const float z = depth[p];

    // --- 3x3 inverse of intrinsics (adjugate; uniform values) ---
    const float a00=intr[0], a01=intr[1], a02=intr[2];
    const float a10=intr[3], a11=intr[4], a12=intr[5];
    const float a20=intr[6], a21=intr[7], a22=intr[8];
    const float det = a00*(a11*a22 - a12*a21)
                    - a01*(a10*a22 - a12*a20)
                    + a02*(a10*a21 - a11*a20);
    const float id = 1.0f / det;
    const float i00 = (a11*a22 - a12*a21)*id;
    const float i01 = (a02*a21 - a01*a22)*id;
    const float i02 = (a01*a12 - a02*a11)*id;
    const float i10 = (a12*a20 - a10*a22)*id;
    const float i11 = (a00*a22 - a02*a20)*id;
    const float i12 = (a02*a10 - a00*a12)*id;
    const float i20 = (a10*a21 - a11*a20)*id;
    const float i21 = (a01*a20 - a00*a21)*id;
    const float i22 = (a00*a11 - a01*a10)*id;

    // pts_p = (u*z, v*z, z)
    const float up = (float)col * z;
    const float vp = (float)row * z;
    const float pcx = i00*up + i01*vp + i02*z;
    const float pcy = i10*up + i11*vp + i12*z;
    const float pcz = i20*up + i21*vp + i22*z;

    // world coords = (E @ [pc,1])[:3]
    const float cwx = extr[0]*pcx + extr[1]*pcy + extr[2]*pcz  + extr[3];
    const float cwy = extr[4]*pcx + extr[5]*pcy + extr[6]*pcz  + extr[7];
    const float cwz = extr[8]*pcx + extr[9]*pcy + extr[10]*pcz + extr[11];

    const float ox = origin[0], oy = origin[1], oz = origin[2];
    const float res = resolution[0];

    // voxel coords
    const float cvx = (cwx - ox) / res;
    const float cvy = (cwy - oy) / res;
    const float cvz = (cwz - oz) / res;
    const float evx = (extr[3]  - ox) / res;
    const float evy = (extr[7]  - oy) / res;
    const float evz = (extr[11] - oz) / res;

    float dx = cvx - evx, dy = cvy - evy, dz = cvz - evz;
    const float nrm = sqrtf(dx*dx + dy*dy + dz*dz);
    const float dn  = fmaxf(nrm, 1e-12f);
    dx /= dn; dy /= dn; dz /= dn;

    const float offs = (float)(s - 4);   // offs in [-4,4]
    const float pt[3] = { cvx + offs*dx, cvy + offs*dy, cvz + offs*dz };

    // --- trilinear setup ---
    float alpha[3], nb[3], fidx[3];
    #pragma unroll
    for (int k = 0; k < 3; ++k) {
        const float f  = floorf(pt[k]);
        const float c  = f + 0.5f;
        const float df = c - pt[k];
        nb[k]    = (df > 0.0f) ? 1.0f : ((df < 0.0f) ? -1.0f : 0.0f);
        alpha[k] = fabsf(pt[k] - c);
        fidx[k]  = f;
    }

    // z corner indexes are shared by all 4 (x,y) pairs
    const float fz0 = fidx[2];
    const float fz1 = fidx[2] + nb[2];
    const bool  vz0 = (fz0 >= 0.0f) && (fz0 < (float)VDIM);
    const bool  vz1 = (fz1 >= 0.0f) && (fz1 < (float)VDIM);
    const int   iz0 = (int)fminf(fmaxf(fz0, 0.0f), (float)(VDIM - 1));
    const int   iz1 = (int)fminf(fmaxf(fz1, 0.0f), (float)(VDIM - 1));
    const int   lo  = min(iz0, iz1);
    const int   sel0 = iz0 - lo;         // 0 or 1
    const int   sel1 = iz1 - lo;
    const float az   = alpha[2];
    const float wz0  = 1.0f - az, wz1 = az;

    // phase 1: 4 pair-addresses + weights + validity
    int   pbase[4];
    int   poff[4];                       // unaligned-guard shift (0 or 1)
    float wxy[4];
    bool  vxy[4];
    float indsbuf[24];
    #pragma unroll
    for (int q4 = 0; q4 < 4; ++q4) {
        const float bx = (q4 >> 1) ? 1.0f : 0.0f;
        const float by = (q4 & 1)  ? 1.0f : 0.0f;
        const float fx = fidx[0] + bx * nb[0];
        const float fy = fidx[1] + by * nb[1];
        const bool  vx = (fx >= 0.0f) && (fx < (float)VDIM);
        const bool  vy = (fy >= 0.0f) && (fy < (float)VDIM);
        const int   ix = (int)fminf(fmaxf(fx, 0.0f), (float)(VDIM - 1));
        const int   iy = (int)fminf(fmaxf(fy, 0.0f), (float)(VDIM - 1));
        const float wx = (bx > 0.0f) ? alpha[0] : (1.0f - alpha[0]);
        const float wy = (by > 0.0f) ? alpha[1] : (1.0f - alpha[1]);
        const int   b  = (ix * VDIM + iy) * VDIM;
        pbase[q4] = b;
        poff[q4]  = (b + lo == NVOX - 1) ? 1 : 0;   // only possible when sel0==sel1==0
        wxy[q4]   = wx * wy;
        vxy[q4]   = vx && vy;
        // inds: corners 2*q4 (z-bit 0) and 2*q4+1 (z-bit 1)
        indsbuf[(2*q4)*3 + 0]   = (float)ix;
        indsbuf[(2*q4)*3 + 1]   = (float)iy;
        indsbuf[(2*q4)*3 + 2]   = (float)iz0;
        indsbuf[(2*q4+1)*3 + 0] = (float)ix;
        indsbuf[(2*q4+1)*3 + 1] = (float)iy;
        indsbuf[(2*q4+1)*3 + 2] = (float)iz1;
    }

    // phase 2: 8 paired gathers (dwordx2), all issued back-to-back;
    // NO barrier anywhere below -> these stay in flight until the final consume
    f32x2 v2[4], wv2[4];
    #pragma unroll
    for (int q4 = 0; q4 < 4; ++q4)
        v2[q4]  = *reinterpret_cast<const f32x2*>(vol  + pbase[q4] + lo - poff[q4]);
    #pragma unroll
    for (int q4 = 0; q4 < 4; ++q4)
        wv2[q4] = *reinterpret_cast<const f32x2*>(wvol + pbase[q4] + lo - poff[q4]);

    // phase 3: gather-independent direct stores (small, partial-line -> keep cached)
    out[OFF_RP + tid*3 + 0] = pt[0];
    out[OFF_RP + tid*3 + 1] = pt[1];
    out[OFF_RP + tid*3 + 2] = pt[2];
    if (s == 0) {
        out[OFF_D + p] = z;
        out[OFF_C + p*3 + 0] = cwx;
        out[OFF_C + p*3 + 1] = cwy;
        out[OFF_C + p*3 + 2] = cwz;
    }

    // ---- wave-local LDS transpose: no __syncthreads, lgkmcnt-ordered only ----
    const int w = t >> 6;                // wave 0..3
    const int l = t & 63;                // lane
    f32x4* wlds = lds4 + w * 384;        // wave-private 6 KiB slice

    // phase 4: inds -> wave-local transpose -> coalesced full-line NT stream
    #pragma unroll
    for (int c = 0; c < 6; ++c) {
        f32x4 v4 = { indsbuf[c*4+0], indsbuf[c*4+1], indsbuf[c*4+2], indsbuf[c*4+3] };
        wlds[l*6 + c] = v4;
    }
    f32x4* outI = reinterpret_cast<f32x4*>(out + OFF_I) + gB*6 + w*384;
    #pragma unroll
    for (int k = 0; k < 6; ++k)
        __builtin_nontemporal_store(wlds[k*64 + l], outI + k*64 + l);

    // phase 5: w8 -> wave-local transpose (reuse slice) -> coalesced NT stream
    {
        const float w00 = wxy[0]*wz0, w01 = wxy[0]*wz1;
        const float w10 = wxy[1]*wz0, w11 = wxy[1]*wz1;
        const float w20 = wxy[2]*wz0, w21 = wxy[2]*wz1;
        const float w30 = wxy[3]*wz0, w31 = wxy[3]*wz1;
        f32x4 w0 = { w00, w01, w10, w11 };
        f32x4 w1 = { w20, w21, w30, w31 };
        wlds[l*2 + 0] = w0;
        wlds[l*2 + 1] = w1;
    }
    f32x4* outW = reinterpret_cast<f32x4*>(out + OFF_W8) + gB*2 + w*128;
    __builtin_nontemporal_store(wlds[l],      outW + l);
    __builtin_nontemporal_store(wlds[64 + l], outW + 64 + l);

    // phase 6: consume gathers (first and only vmcnt wait on them)
    float fv = 0.0f, fw = 0.0f;
    #pragma unroll
    for (int q4 = 0; q4 < 4; ++q4) {
        const float wz0e = (vxy[q4] && vz0) ? wxy[q4] * wz0 : 0.0f;
        const float wz1e = (vxy[q4] && vz1) ? wxy[q4] * wz1 : 0.0f;
        const int   e0 = sel0 + poff[q4];
        const int   e1 = sel1 + poff[q4];
        fv += v2[q4][e0]  * wz0e + v2[q4][e1]  * wz1e;
        fw += wv2[q4][e0] * wz0e + wv2[q4][e1] * wz1e;
    }
    __builtin_nontemporal_store(fv, out + OFF_FV + tid);
    __builtin_nontemporal_store(fw, out + OFF_FW + tid);
}

extern "C" void kernel_launch(void* const* d_in, const int* in_sizes, int n_in,
                              void* d_out, int out_size, void* d_ws, size_t ws_size,
                              hipStream_t stream) {
    const float* depth      = (const float*)d_in[0];
    const float* extr       = (const float*)d_in[1];
    const float* intr       = (const float*)d_in[2];
    const float* vol        = (const float*)d_in[3];
    const float* wvol       = (const float*)d_in[4];
    const float* origin     = (const float*)d_in[5];
    const float* resolution = (const float*)d_in[6];
    float* out = (float*)d_out;

    extractor_kernel<<<NBLK, BLOCK, 0, stream>>>(
        depth, extr, intr, vol, wvol, origin, resolution, out);
}